// Round 11
// baseline (6362.515 us; speedup 1.0000x reference)
//
#include <hip/hip_runtime.h>

#define SEQ  512
#define IDIM 256
#define HD   1024
#define BT   256
#define NCLS 10

#define PAIRS 8          // col-group pairs; chains 2p and 2p+1 share a WG
#define GRN   8          // row groups (128 rows each)
#define NWG   (PAIRS*GRN)   // 64 WGs
#define TPB   512           // 8 waves
#define KKH   32            // h kk-blocks (K=1024)
#define KKX   8             // x kk-blocks (K=256)
#define NCG   16            // col groups

typedef __attribute__((ext_vector_type(8))) short short8;
typedef __attribute__((ext_vector_type(4))) float f32x4;
typedef __attribute__((ext_vector_type(4))) unsigned short us4;
typedef __attribute__((ext_vector_type(4))) int i32x4;

// h double buffer, B-fragment order per col-group (R7 layout).
// All cross-WG traffic via system-scope (sc0+sc1) ops at the LLC --
// placement-independent (R5/R7/R10-proven protocol).
__device__ unsigned short g_h[2][NCG][KKH*64*8];
__device__ float g_hfinal[BT][HD];
__device__ int g_wflag[NCG][64];          // per-WAVE flags: [cg][gr*8 + wave]
__device__ unsigned int g_done_all;

__device__ __forceinline__ unsigned short f2bf(float f){
    unsigned int u = __builtin_bit_cast(unsigned int, f);
    u += 0x7fffu + ((u >> 16) & 1u);      // round-to-nearest-even
    return (unsigned short)(u >> 16);
}
__device__ __forceinline__ float fast_tanh(float v){
    float e = __expf(2.0f * v);           // exact: tanh = 1 - 2/(e^2v+1)
    return 1.0f - 2.0f / (e + 1.0f);
}
__device__ __forceinline__ void sys_st64(unsigned short* p, unsigned long long v){
    __hip_atomic_store((unsigned long long*)p, v, __ATOMIC_RELAXED, __HIP_MEMORY_SCOPE_SYSTEM);
}
__device__ __forceinline__ void sys_st32(int* p, int v){
    __hip_atomic_store(p, v, __ATOMIC_RELAXED, __HIP_MEMORY_SCOPE_SYSTEM);
}
__device__ __forceinline__ int sys_ld32(const int* p){
    return __hip_atomic_load(p, __ATOMIC_RELAXED, __HIP_MEMORY_SCOPE_SYSTEM);
}

__global__
__attribute__((amdgpu_flat_work_group_size(TPB, TPB), amdgpu_waves_per_eu(2, 2)))
void rnn_main(
    const float* __restrict__ x, const float* __restrict__ w_hx,
    const float* __restrict__ w_hh, const float* __restrict__ b_h)
{
    __shared__ unsigned short sX[8*KKX*64*8];   // 64 KB W_hx A-frags
    __shared__ unsigned short sBA[KKH*64*8];    // 32 KB chain-A h slab
    __shared__ unsigned short sBB[KKH*64*8];    // 32 KB chain-B h slab

    const int tid  = threadIdx.x;
    const int wg   = blockIdx.x;
    const int pair = wg & (PAIRS-1);
    const int gr   = wg >> 3;
    const int cgA  = pair*2;
    const int cgB  = cgA + 1;
    const int r0   = gr * 128;
    const int l    = tid & 63;
    const int w    = tid >> 6;
    const int rw   = r0 + w*16;
    const int row  = rw + (l & 15);
    const int ko   = (l >> 4) << 3;

    // ---- W_hh -> wa, pinned (compiler spills to AGPRs: on-chip, cheap reload)
    i32x4 wa[KKH];
    #pragma unroll
    for (int kk = 0; kk < KKH; ++kk){
        f32x4 v0 = *(const f32x4*)(w_hh + (size_t)row*HD + kk*32 + ko);
        f32x4 v1 = *(const f32x4*)(w_hh + (size_t)row*HD + kk*32 + ko + 4);
        us4 lo = { f2bf(v0[0]), f2bf(v0[1]), f2bf(v0[2]), f2bf(v0[3]) };
        us4 hi = { f2bf(v1[0]), f2bf(v1[1]), f2bf(v1[2]), f2bf(v1[3]) };
        unsigned long long a = __builtin_bit_cast(unsigned long long, lo);
        unsigned long long b = __builtin_bit_cast(unsigned long long, hi);
        i32x4 q;
        q[0] = (int)(a & 0xffffffffu); q[1] = (int)(a >> 32);
        q[2] = (int)(b & 0xffffffffu); q[3] = (int)(b >> 32);
        wa[kk] = q;
    }
    #pragma unroll
    for (int kk = 0; kk < KKH; ++kk)
        asm volatile("" : "+v"(wa[kk]));

    // ---- W_hx A-frags -> LDS
    #pragma unroll
    for (int xk = 0; xk < KKX; ++xk){
        f32x4 v0 = *(const f32x4*)(w_hx + (size_t)row*IDIM + xk*32 + ko);
        f32x4 v1 = *(const f32x4*)(w_hx + (size_t)row*IDIM + xk*32 + ko + 4);
        short8 a;
        a[0]=(short)f2bf(v0[0]); a[1]=(short)f2bf(v0[1]);
        a[2]=(short)f2bf(v0[2]); a[3]=(short)f2bf(v0[3]);
        a[4]=(short)f2bf(v1[0]); a[5]=(short)f2bf(v1[1]);
        a[6]=(short)f2bf(v1[2]); a[7]=(short)f2bf(v1[3]);
        *(short8*)&sX[(size_t)((w*KKX + xk)*64 + l)*8] = a;
    }

    const f32x4 bias = *(const f32x4*)(b_h + rw + ((l >> 4) << 2));
    const float* xlaneA = x + (size_t)(cgA*16 + (l & 15))*(SEQ*IDIM) + ko;
    const float* xlaneB = x + (size_t)(cgB*16 + (l & 15))*(SEQ*IDIM) + ko;

    // ---- zero own 4 kk-blocks of buf0, both chains (h_init = 0)
    {
        size_t zoff = (size_t)(gr*4)*512 + (size_t)tid*4;
        sys_st64(&g_h[0][cgA][zoff], 0ull);
        sys_st64(&g_h[0][cgB][zoff], 0ull);
    }

    const int rloc  = w*16 + ((l >> 4) << 2);
    const int kkd   = gr*4 + (rloc >> 5);
    const int lnp   = (l & 15) | (((rloc >> 3) & 3) << 4);
    const int sboff = kkd*512 + lnp*8 + (rloc & 7);
    us4 hwA = {0,0,0,0}, hwB = {0,0,0,0};

    asm volatile("s_waitcnt vmcnt(0)" ::: "memory");
    __syncthreads();                          // all waves' zeros + sX staged
    if (l == 0){                              // per-wave flags: buf0 published
        sys_st32(&g_wflag[cgA][gr*8 + w], 1);
        sys_st32(&g_wflag[cgB][gr*8 + w], 1);
    }

    // ---- x-part prologue (t = 0), both chains
    auto xpart = [&](const float* xp) -> f32x4 {
        f32x4 a = bias;
        #pragma unroll
        for (int xk = 0; xk < KKX; ++xk){
            f32x4 v0 = *(const f32x4*)(xp + xk*32);
            f32x4 v1 = *(const f32x4*)(xp + xk*32 + 4);
            short8 bx;
            bx[0]=(short)f2bf(v0[0]); bx[1]=(short)f2bf(v0[1]);
            bx[2]=(short)f2bf(v0[2]); bx[3]=(short)f2bf(v0[3]);
            bx[4]=(short)f2bf(v1[0]); bx[5]=(short)f2bf(v1[1]);
            bx[6]=(short)f2bf(v1[2]); bx[7]=(short)f2bf(v1[3]);
            short8 aw = *(const short8*)&sX[(size_t)((w*KKX + xk)*64 + l)*8];
            a = __builtin_amdgcn_mfma_f32_16x16x32_bf16(aw, bx, a, 0, 0, 0);
        }
        return a;
    };
    f32x4 accXA = xpart(xlaneA);
    f32x4 accXB = xpart(xlaneB);

    // ---- one phase = one chain's step. 2 phases/t; sync latency of one
    // chain hides under the other chain's work.
    auto phase = [&](int cg, unsigned short* sBc, f32x4& accX, us4& hwp,
                     const float* xlane, int t, int rb){
        // wait (per-wave): poll producer-WG w's 8 wave-flags, then stage
        if (w != gr){
            const int val = t + 1;
            const int* pp = &g_wflag[cg][w*8 + (l & 7)];
            int guard = 0;
            for (;;){
                int f = sys_ld32(pp);
                if (__all(f >= val)) break;
                if (++guard > (1 << 20)) break;   // hang safety
            }
        }
        *(us4*)&sBc[sboff] = hwp;                 // self blocks from registers
        if (w != gr){
            const unsigned short* pa = &g_h[rb][cg][(size_t)(w*4)*512 + l*8];
            i32x4 v0, v1, v2, v3;
            asm volatile("global_load_dwordx4 %0, %1, off sc0 sc1" : "=v"(v0) : "v"(pa));
            asm volatile("global_load_dwordx4 %0, %1, off sc0 sc1" : "=v"(v1) : "v"(pa + 512));
            asm volatile("global_load_dwordx4 %0, %1, off sc0 sc1" : "=v"(v2) : "v"(pa + 1024));
            asm volatile("global_load_dwordx4 %0, %1, off sc0 sc1" : "=v"(v3) : "v"(pa + 1536));
            asm volatile("s_waitcnt vmcnt(0)" ::: "memory");
            *(i32x4*)&sBc[(size_t)(w*4+0)*512 + l*8] = v0;
            *(i32x4*)&sBc[(size_t)(w*4+1)*512 + l*8] = v1;
            *(i32x4*)&sBc[(size_t)(w*4+2)*512 + l*8] = v2;
            *(i32x4*)&sBc[(size_t)(w*4+3)*512 + l*8] = v3;
        }
        __syncthreads();

        f32x4 acc = accX;
        #pragma unroll
        for (int kk = 0; kk < KKH; ++kk){
            short8 b = *(const short8*)&sBc[(size_t)(kk*64 + l)*8];
            acc = __builtin_amdgcn_mfma_f32_16x16x32_bf16(
                      __builtin_bit_cast(short8, wa[kk]), b, acc, 0, 0, 0);
        }
        float h0 = fast_tanh(acc[0]);
        float h1 = fast_tanh(acc[1]);
        float h2 = fast_tanh(acc[2]);
        float h3 = fast_tanh(acc[3]);

        if (t < SEQ-1){
            us4 hw = { f2bf(h0), f2bf(h1), f2bf(h2), f2bf(h3) };
            sys_st64(&g_h[rb ^ 1][cg][sboff],
                     __builtin_bit_cast(unsigned long long, hw));
            hwp = hw;
            // x-part for t+1 computed under the h-store's LLC ack
            accX = xpart(xlane + (size_t)(t+1)*IDIM);
            asm volatile("s_waitcnt vmcnt(0)" ::: "memory");  // per-wave drain
            if (l == 0) sys_st32(&g_wflag[cg][gr*8 + w], t + 2);
        } else {
            f32x4 hf = {h0, h1, h2, h3};
            *(f32x4*)&g_hfinal[cg*16 + (l & 15)][r0 + rloc] = hf;
        }
    };

    for (int t = 0; t < SEQ; ++t){
        const int rb = t & 1;
        phase(cgA, sBA, accXA, hwA, xlaneA, t, rb);
        phase(cgB, sBB, accXB, hwB, xlaneB, t, rb);
    }

    // ---- epilogue: last WG resets all flags for graph replay
    __syncthreads();
    if (tid == 0){
        unsigned old = __hip_atomic_fetch_add(&g_done_all, 1u,
                           __ATOMIC_ACQ_REL, __HIP_MEMORY_SCOPE_SYSTEM);
        if (old == NWG - 1){
            for (int g = 0; g < NCG; ++g)
                for (int i = 0; i < 64; ++i)
                    sys_st32(&g_wflag[g][i], 0);
            __hip_atomic_store(&g_done_all, 0u, __ATOMIC_RELAXED, __HIP_MEMORY_SCOPE_SYSTEM);
        }
    }
}

// p = w_ph @ h_final + b_p ; out[b][c]
__global__ __launch_bounds__(256, 1) void proj_kernel(
    const float* __restrict__ w_ph, const float* __restrict__ b_p, float* __restrict__ out)
{
    const int b   = blockIdx.x;
    const int tid = threadIdx.x;
    const int l   = tid & 63;
    const int wv  = tid >> 6;
    __shared__ float red[4];
    f32x4 hv = *(const f32x4*)(&g_hfinal[b][0] + tid*4);
    for (int c = 0; c < NCLS; ++c){
        f32x4 wvv = *(const f32x4*)(w_ph + c*HD + tid*4);
        float s = hv[0]*wvv[0] + hv[1]*wvv[1] + hv[2]*wvv[2] + hv[3]*wvv[3];
        #pragma unroll
        for (int off = 32; off; off >>= 1) s += __shfl_down(s, off, 64);
        if (l == 0) red[wv] = s;
        __syncthreads();
        if (tid == 0) out[b*NCLS + c] = red[0] + red[1] + red[2] + red[3] + b_p[c];
        __syncthreads();
    }
}

extern "C" void kernel_launch(void* const* d_in, const int* in_sizes, int n_in,
                              void* d_out, int out_size, void* d_ws, size_t ws_size,
                              hipStream_t stream) {
    const float* x    = (const float*)d_in[0];
    const float* w_hx = (const float*)d_in[1];
    const float* w_hh = (const float*)d_in[2];
    const float* b_h  = (const float*)d_in[3];
    const float* w_ph = (const float*)d_in[4];
    const float* b_p  = (const float*)d_in[5];

    void* args[] = { (void*)&x, (void*)&w_hx, (void*)&w_hh, (void*)&b_h };
    hipError_t err = hipLaunchCooperativeKernel((void*)rnn_main, dim3(NWG), dim3(TPB),
                                                args, 0, stream);
    if (err != hipSuccess) {
        rnn_main<<<dim3(NWG), dim3(TPB), 0, stream>>>(x, w_hx, w_hh, b_h);
    }
    proj_kernel<<<dim3(BT), dim3(256), 0, stream>>>(w_ph, b_p, (float*)d_out);
}

// Round 12
// 2620.907 us; speedup vs baseline: 2.4276x; 2.4276x over previous
//
#include <hip/hip_runtime.h>

#define SEQ  512
#define IDIM 256
#define HD   1024
#define BT   256
#define NCLS 10

#define GR    8         // row groups (128 rows each)
#define GB    16        // batch groups (16 cols each)
#define NWG   (GR*GB)   // 128 WGs
#define TPB   512       // 8 waves
#define KKH   32        // h kk-blocks (K=1024)
#define KKX   8         // x kk-blocks (K=256)
#define NSLOT 4         // h slot ring depth
#define SENT  0x7F80    // bf16 +inf: impossible as tanh output

typedef __attribute__((ext_vector_type(8))) short short8;
typedef __attribute__((ext_vector_type(4))) float f32x4;
typedef __attribute__((ext_vector_type(4))) unsigned short us4;
typedef __attribute__((ext_vector_type(4))) int i32x4;

// h slot ring, B-fragment order per col-group. h_t lives in slot t%4.
// NO flags: data is self-validating via the SENT sentinel. All cross-WG
// traffic is system-scope (sc0+sc1) at the LLC -- placement-independent.
__device__ unsigned short g_h[NSLOT][GB][KKH*64*8];
__device__ float g_hfinal[BT][HD];
__device__ unsigned g_bar, g_done_all;      // one-time grid barrier + reset

__device__ __forceinline__ unsigned short f2bf(float f){
    unsigned int u = __builtin_bit_cast(unsigned int, f);
    u += 0x7fffu + ((u >> 16) & 1u);        // round-to-nearest-even
    return (unsigned short)(u >> 16);
}
__device__ __forceinline__ float fast_tanh(float v){
    float e = __expf(2.0f * v);             // exact: tanh = 1 - 2/(e^2v+1)
    return 1.0f - 2.0f / (e + 1.0f);
}
__device__ __forceinline__ void sys_st64(unsigned short* p, unsigned long long v){
    __hip_atomic_store((unsigned long long*)p, v, __ATOMIC_RELAXED, __HIP_MEMORY_SCOPE_SYSTEM);
}

__global__
__attribute__((amdgpu_flat_work_group_size(TPB, TPB), amdgpu_waves_per_eu(2, 2)))
void rnn_main(
    const float* __restrict__ x, const float* __restrict__ w_hx,
    const float* __restrict__ w_hh, const float* __restrict__ b_h)
{
    __shared__ unsigned short sX[8*KKX*64*8];     // 64 KB W_hx A-frags
    __shared__ unsigned short sB2[2][KKH*64*8];   // 2 x 32 KB h slabs (alternate)

    const int tid = threadIdx.x;
    const int wg  = blockIdx.x;
    const int gbg = wg & (GB-1);
    const int gr  = wg >> 4;
    const int r0  = gr * 128;
    const int b0  = gbg * 16;
    const int l   = tid & 63;
    const int w   = tid >> 6;
    const int rw  = r0 + w*16;
    const int row = rw + (l & 15);
    const int ko  = (l >> 4) << 3;

    // ---- W_hh -> wa, pinned (spills to AGPR: on-chip, cheap reload; R10-proven)
    i32x4 wa[KKH];
    #pragma unroll
    for (int kk = 0; kk < KKH; ++kk){
        f32x4 v0 = *(const f32x4*)(w_hh + (size_t)row*HD + kk*32 + ko);
        f32x4 v1 = *(const f32x4*)(w_hh + (size_t)row*HD + kk*32 + ko + 4);
        us4 lo = { f2bf(v0[0]), f2bf(v0[1]), f2bf(v0[2]), f2bf(v0[3]) };
        us4 hi = { f2bf(v1[0]), f2bf(v1[1]), f2bf(v1[2]), f2bf(v1[3]) };
        unsigned long long a = __builtin_bit_cast(unsigned long long, lo);
        unsigned long long b = __builtin_bit_cast(unsigned long long, hi);
        i32x4 q;
        q[0] = (int)(a & 0xffffffffu); q[1] = (int)(a >> 32);
        q[2] = (int)(b & 0xffffffffu); q[3] = (int)(b >> 32);
        wa[kk] = q;
    }
    #pragma unroll
    for (int kk = 0; kk < KKH; ++kk)
        asm volatile("" : "+v"(wa[kk]));

    // ---- W_hx A-frags -> LDS
    #pragma unroll
    for (int xk = 0; xk < KKX; ++xk){
        f32x4 v0 = *(const f32x4*)(w_hx + (size_t)row*IDIM + xk*32 + ko);
        f32x4 v1 = *(const f32x4*)(w_hx + (size_t)row*IDIM + xk*32 + ko + 4);
        short8 a;
        a[0]=(short)f2bf(v0[0]); a[1]=(short)f2bf(v0[1]);
        a[2]=(short)f2bf(v0[2]); a[3]=(short)f2bf(v0[3]);
        a[4]=(short)f2bf(v1[0]); a[5]=(short)f2bf(v1[1]);
        a[6]=(short)f2bf(v1[2]); a[7]=(short)f2bf(v1[3]);
        *(short8*)&sX[(size_t)((w*KKX + xk)*64 + l)*8] = a;
    }

    const f32x4 bias = *(const f32x4*)(b_h + rw + ((l >> 4) << 2));
    const float* xlane = x + (size_t)(b0 + (l & 15))*(SEQ*IDIM) + ko;

    // this thread's h word position (B-frag order), owned across all slots
    const int rloc  = w*16 + ((l >> 4) << 2);
    const int kkd   = gr*4 + (rloc >> 5);
    const int lnp   = (l & 15) | (((rloc >> 3) & 3) << 4);
    const int sboff = kkd*512 + lnp*8 + (rloc & 7);
    us4 hw_prev = {0, 0, 0, 0};

    // ---- init ring: slot 0 = zeros (h_0 data), slots 1..3 = sentinel
    sys_st64(&g_h[0][gbg][sboff], 0ull);
    {
        int sv = SENT;
        #pragma unroll
        for (int s = 1; s < NSLOT; ++s){
            unsigned short* p = &g_h[s][gbg][sboff];
            asm volatile("global_store_short %0, %1, off sc0 sc1" :: "v"(p), "v"(sv) : "memory");
        }
    }
    asm volatile("s_waitcnt vmcnt(0)" ::: "memory");
    __syncthreads();

    // ---- one-time grid barrier: all inits visible before anyone polls
    if (tid == 0){
        __hip_atomic_fetch_add(&g_bar, 1u, __ATOMIC_ACQ_REL, __HIP_MEMORY_SCOPE_SYSTEM);
        int guard = 0;
        while (__hip_atomic_load(&g_bar, __ATOMIC_ACQUIRE, __HIP_MEMORY_SCOPE_SYSTEM) < NWG
               && ++guard < (1 << 22)) { }
    }
    __syncthreads();

    // ---- x-part for t=0
    auto xpart = [&](const float* xp) -> f32x4 {
        f32x4 a = bias;
        #pragma unroll
        for (int xk = 0; xk < KKX; ++xk){
            f32x4 v0 = *(const f32x4*)(xp + xk*32);
            f32x4 v1 = *(const f32x4*)(xp + xk*32 + 4);
            short8 bx;
            bx[0]=(short)f2bf(v0[0]); bx[1]=(short)f2bf(v0[1]);
            bx[2]=(short)f2bf(v0[2]); bx[3]=(short)f2bf(v0[3]);
            bx[4]=(short)f2bf(v1[0]); bx[5]=(short)f2bf(v1[1]);
            bx[6]=(short)f2bf(v1[2]); bx[7]=(short)f2bf(v1[3]);
            short8 aw = *(const short8*)&sX[(size_t)((w*KKX + xk)*64 + l)*8];
            a = __builtin_amdgcn_mfma_f32_16x16x32_bf16(aw, bx, a, 0, 0, 0);
        }
        return a;
    };
    f32x4 accX = xpart(xlane);

    for (int t = 0; t < SEQ; ++t){
        const int slot  = t & 3;
        const int nslot = (t + 1) & 3;
        const int pslot = (t + 3) & 3;            // == (t-1) mod 4
        unsigned short* sB = &sB2[t & 1][0];

        // ---- staging: wave w owns producer w's 4 kk-blocks.
        // Self word from registers; foreign blocks polled until sentinel-free
        // (detection and data arrive in the SAME loads -- no flag hops).
        *(us4*)&sB[sboff] = hw_prev;
        if (w != gr){
            const unsigned short* base = &g_h[slot][gbg][(size_t)(w*4)*512 + l*8];
            i32x4 v0, v1, v2, v3;
            int guard = 0;
            for (;;){
                asm volatile(
                    "global_load_dwordx4 %0, %4, off sc0 sc1\n\t"
                    "global_load_dwordx4 %1, %4, off offset:1024 sc0 sc1\n\t"
                    "global_load_dwordx4 %2, %4, off offset:2048 sc0 sc1\n\t"
                    "global_load_dwordx4 %3, %4, off offset:3072 sc0 sc1"
                    : "=&v"(v0), "=&v"(v1), "=&v"(v2), "=&v"(v3)
                    : "v"(base));
                asm volatile("s_waitcnt vmcnt(0)" ::: "memory");
                bool ok = ((v0[0] & 0xFFFF) != SENT) && ((v0[2] & 0xFFFF) != SENT)
                       && ((v1[0] & 0xFFFF) != SENT) && ((v1[2] & 0xFFFF) != SENT)
                       && ((v2[0] & 0xFFFF) != SENT) && ((v2[2] & 0xFFFF) != SENT)
                       && ((v3[0] & 0xFFFF) != SENT) && ((v3[2] & 0xFFFF) != SENT);
                if (__all(ok)) break;
                if (++guard > (1 << 20)) break;   // hang safety
            }
            *(i32x4*)&sB[(size_t)(w*4+0)*512 + l*8] = v0;
            *(i32x4*)&sB[(size_t)(w*4+1)*512 + l*8] = v1;
            *(i32x4*)&sB[(size_t)(w*4+2)*512 + l*8] = v2;
            *(i32x4*)&sB[(size_t)(w*4+3)*512 + l*8] = v3;
        } else {
            asm volatile("s_waitcnt vmcnt(0)" ::: "memory");  // orders own stores
        }
        __syncthreads();   // all blocks staged; also: all producers wrote h_t
                           // => slot (t-1) fully consumed => safe to re-arm it

        // ---- re-arm slot (t-1): 2B sentinel into own word (fire & forget;
        // ordered before our t+3 data store by the staging vmcnt(0)s)
        {
            int sv = SENT;
            unsigned short* p = &g_h[pslot][gbg][sboff];
            asm volatile("global_store_short %0, %1, off sc0 sc1" :: "v"(p), "v"(sv) : "memory");
        }

        // ---- recurrent MFMAs: K = 1024
        f32x4 acc = accX;
        #pragma unroll
        for (int kk = 0; kk < KKH; ++kk){
            short8 b = *(const short8*)&sB[(size_t)(kk*64 + l)*8];
            acc = __builtin_amdgcn_mfma_f32_16x16x32_bf16(
                      __builtin_bit_cast(short8, wa[kk]), b, acc, 0, 0, 0);
        }
        float h0 = fast_tanh(acc[0]);
        float h1 = fast_tanh(acc[1]);
        float h2 = fast_tanh(acc[2]);
        float h3 = fast_tanh(acc[3]);

        if (t < SEQ-1){
            us4 hw = { f2bf(h0), f2bf(h1), f2bf(h2), f2bf(h3) };
            sys_st64(&g_h[nslot][gbg][sboff],
                     __builtin_bit_cast(unsigned long long, hw));  // fire & forget
            hw_prev = hw;
            accX = xpart(xlane + (size_t)(t+1)*IDIM);   // overlaps store flight
        } else {
            f32x4 hf = {h0, h1, h2, h3};
            *(f32x4*)&g_hfinal[b0 + (l & 15)][r0 + rloc] = hf;
        }
    }

    // ---- epilogue: last WG resets the two counters for graph replay
    __syncthreads();
    if (tid == 0){
        unsigned old = __hip_atomic_fetch_add(&g_done_all, 1u,
                           __ATOMIC_ACQ_REL, __HIP_MEMORY_SCOPE_SYSTEM);
        if (old == NWG - 1){
            __hip_atomic_store(&g_bar,      0u, __ATOMIC_RELAXED, __HIP_MEMORY_SCOPE_SYSTEM);
            __hip_atomic_store(&g_done_all, 0u, __ATOMIC_RELAXED, __HIP_MEMORY_SCOPE_SYSTEM);
        }
    }
}

// p = w_ph @ h_final + b_p ; out[b][c]
__global__ __launch_bounds__(256, 1) void proj_kernel(
    const float* __restrict__ w_ph, const float* __restrict__ b_p, float* __restrict__ out)
{
    const int b   = blockIdx.x;
    const int tid = threadIdx.x;
    const int l   = tid & 63;
    const int wv  = tid >> 6;
    __shared__ float red[4];
    f32x4 hv = *(const f32x4*)(&g_hfinal[b][0] + tid*4);
    for (int c = 0; c < NCLS; ++c){
        f32x4 wvv = *(const f32x4*)(w_ph + c*HD + tid*4);
        float s = hv[0]*wvv[0] + hv[1]*wvv[1] + hv[2]*wvv[2] + hv[3]*wvv[3];
        #pragma unroll
        for (int off = 32; off; off >>= 1) s += __shfl_down(s, off, 64);
        if (l == 0) red[wv] = s;
        __syncthreads();
        if (tid == 0) out[b*NCLS + c] = red[0] + red[1] + red[2] + red[3] + b_p[c];
        __syncthreads();
    }
}

extern "C" void kernel_launch(void* const* d_in, const int* in_sizes, int n_in,
                              void* d_out, int out_size, void* d_ws, size_t ws_size,
                              hipStream_t stream) {
    const float* x    = (const float*)d_in[0];
    const float* w_hx = (const float*)d_in[1];
    const float* w_hh = (const float*)d_in[2];
    const float* b_h  = (const float*)d_in[3];
    const float* w_ph = (const float*)d_in[4];
    const float* b_p  = (const float*)d_in[5];

    void* args[] = { (void*)&x, (void*)&w_hx, (void*)&w_hh, (void*)&b_h };
    hipError_t err = hipLaunchCooperativeKernel((void*)rnn_main, dim3(NWG), dim3(TPB),
                                                args, 0, stream);
    if (err != hipSuccess) {
        rnn_main<<<dim3(NWG), dim3(TPB), 0, stream>>>(x, w_hx, w_hh, b_h);
    }
    proj_kernel<<<dim3(BT), dim3(256), 0, stream>>>(w_ph, b_p, (float*)d_out);
}